// Round 3
// baseline (767.520 us; speedup 1.0000x reference)
//
#include <hip/hip_runtime.h>
#include <cmath>

#define NE 32
#define NC 4096
#define ND 256
#define NH 1024
#define BM 64            // x/y rows per workgroup
#define BH 128           // h columns per step
#define NSTEP (NH / BH)  // 8
#define NWAVE 8
#define THREADS (NWAVE * 64)
#define NWG (NE * NC / BM)  // 2048
#define TOTY ((size_t)NE * NC * ND)

typedef float  float4v __attribute__((ext_vector_type(4)));
typedef float  f32x4   __attribute__((ext_vector_type(4)));
typedef short  short8v __attribute__((ext_vector_type(8)));
typedef short  short4v __attribute__((ext_vector_type(4)));
typedef __bf16 bf16x8  __attribute__((ext_vector_type(8)));

__device__ inline unsigned short f2bf(float f) {
  unsigned int u = __float_as_uint(f);
  u += 0x7fffu + ((u >> 16) & 1u);   // round-to-nearest-even
  return (unsigned short)(u >> 16);
}

__device__ inline f32x4 mfma16(bf16x8 a, bf16x8 b, f32x4 c) {
  return __builtin_amdgcn_mfma_f32_16x16x32_bf16(a, b, c, 0, 0, 0);
}

__device__ inline float gelu_exact(float v) {
  return 0.5f * v * (1.0f + erff(v * 0.70710678118f));
}

// ---------------- pre-transpose + bf16 cast: src [E][R][Cc] f32 -> dst [E][Cc][R] bf16 ----------------
__global__ void transpose_cvt(const float* __restrict__ src, unsigned short* __restrict__ dst,
                              int R, int Cc) {
  __shared__ alignas(16) float tile[32][33];
  int tilesC = Cc >> 5;
  int per_e  = (R >> 5) * tilesC;
  int e  = blockIdx.x / per_e;
  int t  = blockIdx.x % per_e;
  int tr = t / tilesC, tc = t % tilesC;
  const float* s = src + (size_t)e * R * Cc;
  unsigned short* d = dst + (size_t)e * R * Cc;
  int tx = threadIdx.x & 31, ty = threadIdx.x >> 5;
  for (int i = ty; i < 32; i += 8)
    tile[i][tx] = s[(size_t)(tr * 32 + i) * Cc + tc * 32 + tx];
  __syncthreads();
  for (int i = ty; i < 32; i += 8)
    d[(size_t)(tc * 32 + i) * R + tr * 32 + tx] = f2bf(tile[tx][i]);
}

__global__ void zero_scalar(float* p) {
  if (threadIdx.x == 0 && blockIdx.x == 0) *p = 0.0f;
}

// ---------------- fused per-expert MLP (fast path, needs 32MiB ws) ----------------
// GEMM1: hT[c][r] = sum_k w1T[c][k] * x[r][k]   (A = w1T, B = x-in-regs)
// GEMM2: yT[d][r] = sum_c w2T[d][c] * h[r][c]   (A = w2T, B = h-in-LDS)
__global__ __launch_bounds__(THREADS, 2) void experts_mlp(
    const float* __restrict__ x, const float* __restrict__ b1,
    const float* __restrict__ b2, const float* __restrict__ bungee,
    const unsigned short* __restrict__ w1t, const unsigned short* __restrict__ w2t,
    float* __restrict__ y, float* __restrict__ sumsq) {
  __shared__ alignas(16) short h_lds[BM][BH + 8];
  __shared__ alignas(16) float red[NWAVE];

  // XCD-chunked swizzle: 2048 wgs, 8 XCDs, 256 consecutive wgs per XCD (4 experts/XCD)
  int bid = blockIdx.x;
  int wg  = (bid & 7) * (NWG / 8) + (bid >> 3);
  int e   = wg >> 6;        // / (NC/BM = 64)
  int r0  = (wg & 63) * BM;

  int tid  = threadIdx.x;
  int wid  = tid >> 6;
  int lane = tid & 63;
  int lr   = lane & 15;
  int lg   = lane >> 4;

  // ---- x fragments (B operand GEMM1), loaded once: xf[nf][ks] = x[r0+nf*16+lr][ks*32+lg*8 ..+7]
  bf16x8 xf[4][8];
  {
    const float* xb = x + ((size_t)e * NC + r0) * ND;
    #pragma unroll
    for (int nf = 0; nf < 4; ++nf) {
      const float* xr = xb + (size_t)(nf * 16 + lr) * ND;
      #pragma unroll
      for (int ks = 0; ks < 8; ++ks) {
        float4v u = *(const float4v*)(xr + ks * 32 + lg * 8);
        float4v v = *(const float4v*)(xr + ks * 32 + lg * 8 + 4);
        short8v s;
        s[0] = (short)f2bf(u[0]); s[1] = (short)f2bf(u[1]);
        s[2] = (short)f2bf(u[2]); s[3] = (short)f2bf(u[3]);
        s[4] = (short)f2bf(v[0]); s[5] = (short)f2bf(v[1]);
        s[6] = (short)f2bf(v[2]); s[7] = (short)f2bf(v[3]);
        xf[nf][ks] = __builtin_bit_cast(bf16x8, s);
      }
    }
  }

  f32x4 zero4 = {0.f, 0.f, 0.f, 0.f};
  f32x4 acc2[2][4];
  #pragma unroll
  for (int mf = 0; mf < 2; ++mf)
    #pragma unroll
    for (int nf = 0; nf < 4; ++nf) acc2[mf][nf] = zero4;

  const unsigned short* w1row = w1t + ((size_t)e * NH + wid * 16 + lr) * ND;
  const unsigned short* w2row = w2t + ((size_t)e * ND + wid * 32 + lr) * NH;

  for (int hs = 0; hs < NSTEP; ++hs) {
    // ---- GEMM1: this wave computes hT cols [hs*BH + wid*16, +16) x rows [0,64)
    bf16x8 a1[8];
    const unsigned short* wr = w1row + (size_t)hs * BH * ND;
    #pragma unroll
    for (int ks = 0; ks < 8; ++ks)
      a1[ks] = __builtin_bit_cast(bf16x8, *(const short8v*)(wr + ks * 32 + lg * 8));

    f32x4 acc1[4];
    #pragma unroll
    for (int nf = 0; nf < 4; ++nf) acc1[nf] = zero4;
    #pragma unroll
    for (int ks = 0; ks < 8; ++ks)
      #pragma unroll
      for (int nf = 0; nf < 4; ++nf)
        acc1[nf] = mfma16(a1[ks], xf[nf][ks], acc1[nf]);

    // ---- bias + exact GELU -> h_lds (contiguous b64 per fragment)
    // C/D layout (m89-verified): col(=r here)=lane&15, row(=c here)=(lane>>4)*4+reg
    int clocal = wid * 16 + lg * 4;
    const float* b1p = b1 + (size_t)e * NH + hs * BH + clocal;
    float4v bv = *(const float4v*)b1p;
    #pragma unroll
    for (int nf = 0; nf < 4; ++nf) {
      short4v p;
      #pragma unroll
      for (int reg = 0; reg < 4; ++reg)
        p[reg] = (short)f2bf(gelu_exact(acc1[nf][reg] + bv[reg]));
      *(short4v*)&h_lds[nf * 16 + lr][clocal] = p;
    }
    __syncthreads();

    // ---- GEMM2: this wave computes yT rows d in [wid*32, +32) x r [0,64), k over this h block
    const unsigned short* w2p = w2row + (size_t)hs * BH;
    #pragma unroll
    for (int ks = 0; ks < 4; ++ks) {
      bf16x8 a20 = __builtin_bit_cast(bf16x8, *(const short8v*)(w2p + ks * 32 + lg * 8));
      bf16x8 a21 = __builtin_bit_cast(bf16x8, *(const short8v*)(w2p + (size_t)16 * NH + ks * 32 + lg * 8));
      #pragma unroll
      for (int nf = 0; nf < 4; ++nf) {
        bf16x8 hb = __builtin_bit_cast(bf16x8, *(const short8v*)&h_lds[nf * 16 + lr][ks * 32 + lg * 8]);
        acc2[0][nf] = mfma16(a20, hb, acc2[0][nf]);
        acc2[1][nf] = mfma16(a21, hb, acc2[1][nf]);
      }
    }
    __syncthreads();
  }

  // ---- epilogue: bias2 + bungee scale + store + sum of squares
  float bg = bungee[e];
  float ss = 0.0f;
  int dbase = wid * 32 + lg * 4;
  #pragma unroll
  for (int mf = 0; mf < 2; ++mf) {
    int dd = dbase + mf * 16;
    float4v b2v = *(const float4v*)(b2 + (size_t)e * ND + dd);
    #pragma unroll
    for (int nf = 0; nf < 4; ++nf) {
      int r = r0 + nf * 16 + lr;
      float4v o;
      #pragma unroll
      for (int reg = 0; reg < 4; ++reg) {
        float v = (acc2[mf][nf][reg] + b2v[reg]) * bg;
        o[reg] = v;
        ss += v * v;
      }
      *(float4v*)(y + ((size_t)e * NC + r) * ND + dd) = o;
    }
  }
  #pragma unroll
  for (int off = 32; off > 0; off >>= 1) ss += __shfl_down(ss, off);
  if (lane == 0) red[wid] = ss;
  __syncthreads();
  if (tid == 0) {
    float t = 0.f;
    #pragma unroll
    for (int i = 0; i < NWAVE; ++i) t += red[i];
    atomicAdd(sumsq, t);
  }
}

// ---------------- fallback path: zero workspace, fp32 VALU, 8 rows/block ----------------
#define FBROWS 8
__global__ __launch_bounds__(256) void fb_mlp(
    const float* __restrict__ x, const float* __restrict__ w1, const float* __restrict__ b1,
    const float* __restrict__ w2, const float* __restrict__ b2, const float* __restrict__ bungee,
    float* __restrict__ y, float* __restrict__ sumsq) {
  __shared__ alignas(16) float xs[FBROWS][ND];
  __shared__ alignas(16) float hsh[FBROWS][NH];
  __shared__ float red[4];
  int tid = threadIdx.x;
  int e  = blockIdx.x / (NC / FBROWS);
  int r0 = (blockIdx.x % (NC / FBROWS)) * FBROWS;

  for (int i = tid; i < FBROWS * ND; i += 256)
    ((float*)xs)[i] = x[((size_t)e * NC + r0) * ND + i];
  __syncthreads();

  for (int c = tid; c < NH; c += 256) {
    float acc[FBROWS];
    float bb = b1[(size_t)e * NH + c];
    #pragma unroll
    for (int rr = 0; rr < FBROWS; ++rr) acc[rr] = bb;
    for (int k = 0; k < ND; ++k) {
      float w = w1[((size_t)e * ND + k) * NH + c];
      #pragma unroll
      for (int rr = 0; rr < FBROWS; ++rr) acc[rr] += xs[rr][k] * w;
    }
    #pragma unroll
    for (int rr = 0; rr < FBROWS; ++rr) hsh[rr][c] = gelu_exact(acc[rr]);
  }
  __syncthreads();

  int d = tid;  // ND == 256 == blockDim
  float acc[FBROWS];
  float bb = b2[(size_t)e * ND + d];
  #pragma unroll
  for (int rr = 0; rr < FBROWS; ++rr) acc[rr] = bb;
  for (int c = 0; c < NH; ++c) {
    float w = w2[((size_t)e * NH + c) * ND + d];
    #pragma unroll
    for (int rr = 0; rr < FBROWS; ++rr) acc[rr] += hsh[rr][c] * w;
  }
  float bg = bungee[e];
  float ss = 0.f;
  #pragma unroll
  for (int rr = 0; rr < FBROWS; ++rr) {
    float v = acc[rr] * bg;
    y[((size_t)e * NC + r0 + rr) * ND + d] = v;
    ss += v * v;
  }
  #pragma unroll
  for (int off = 32; off > 0; off >>= 1) ss += __shfl_down(ss, off);
  if ((tid & 63) == 0) red[tid >> 6] = ss;
  __syncthreads();
  if (tid == 0) atomicAdd(sumsq, red[0] + red[1] + red[2] + red[3]);
}

// ---------------- scalars (in-place: sumsq lives at out_scalars[0]) ----------------
__global__ void finalize(const float* __restrict__ bungee, float* __restrict__ out_scalars) {
  if (threadIdx.x == 0 && blockIdx.x == 0) {
    float ss = out_scalars[0];
    out_scalars[0] = sqrtf(ss / (float)TOTY);
    float m = 0.f, mn = bungee[0], mx = bungee[0];
    for (int i = 0; i < NE; ++i) {
      float b = bungee[i];
      m += b; mn = fminf(mn, b); mx = fmaxf(mx, b);
    }
    out_scalars[1] = m / (float)NE;
    out_scalars[2] = mn;
    out_scalars[3] = mx;
  }
}

extern "C" void kernel_launch(void* const* d_in, const int* in_sizes, int n_in,
                              void* d_out, int out_size, void* d_ws, size_t ws_size,
                              hipStream_t stream) {
  (void)in_sizes; (void)n_in; (void)out_size;
  const float* x  = (const float*)d_in[0];
  const float* w1 = (const float*)d_in[1];
  const float* b1 = (const float*)d_in[2];
  const float* w2 = (const float*)d_in[3];
  const float* b2 = (const float*)d_in[4];
  const float* bg = (const float*)d_in[5];
  float* out = (float*)d_out;
  float* rms_slot = out + TOTY;   // sumsq accumulates here; finalize overwrites

  const size_t WS_NEEDED = (size_t)NE * ND * NH * 2 * 2;  // 32 MiB (bf16 w1t + w2t)

  zero_scalar<<<1, 1, 0, stream>>>(rms_slot);
  if (ws_size >= WS_NEEDED) {
    unsigned short* w1t = (unsigned short*)d_ws;              // [E][H][D] bf16
    unsigned short* w2t = w1t + (size_t)NE * ND * NH;         // [E][D][H] bf16
    transpose_cvt<<<NE * (ND / 32) * (NH / 32), 256, 0, stream>>>(w1, w1t, ND, NH);
    transpose_cvt<<<NE * (NH / 32) * (ND / 32), 256, 0, stream>>>(w2, w2t, NH, ND);
    experts_mlp<<<NWG, THREADS, 0, stream>>>(x, b1, b2, bg, w1t, w2t, out, rms_slot);
  } else {
    fb_mlp<<<NE * NC / FBROWS, 256, 0, stream>>>(x, w1, b1, w2, b2, bg, out, rms_slot);
  }
  finalize<<<1, 64, 0, stream>>>(bg, rms_slot);
}

// Round 6
// 547.171 us; speedup vs baseline: 1.4027x; 1.4027x over previous
//
#include <hip/hip_runtime.h>
#include <cmath>

#define NE 32
#define NC 4096
#define ND 256
#define NH 1024
#define BM 64            // x/y rows per workgroup
#define BH 128           // h columns per step
#define NSTEP (NH / BH)  // 8
#define NWAVE 8
#define THREADS (NWAVE * 64)
#define NWG (NE * NC / BM)  // 2048
#define TOTY ((size_t)NE * NC * ND)

typedef float  float4v __attribute__((ext_vector_type(4)));
typedef float  f32x4   __attribute__((ext_vector_type(4)));
typedef short  short8v __attribute__((ext_vector_type(8)));
typedef short  short4v __attribute__((ext_vector_type(4)));
typedef __bf16 bf16x8  __attribute__((ext_vector_type(8)));
typedef __bf16 bf16x4  __attribute__((ext_vector_type(4)));

__device__ inline unsigned short f2bf(float f) {
  unsigned int u = __float_as_uint(f);
  u += 0x7fffu + ((u >> 16) & 1u);
  return (unsigned short)(u >> 16);
}

__device__ inline f32x4 mfma16(bf16x8 a, bf16x8 b, f32x4 c) {
  return __builtin_amdgcn_mfma_f32_16x16x32_bf16(a, b, c, 0, 0, 0);
}

// Fast exact-GELU: Abramowitz-Stegun 7.1.26 erf (|err|<=1.5e-7), ~13 VALU ops.
__device__ inline float gelu_fast(float v) {
  float u = v * 0.70710678118f;
  float a = fabsf(u);
  float t = __builtin_amdgcn_rcpf(__builtin_fmaf(0.3275911f, a, 1.0f));
  float p = 1.061405429f;
  p = __builtin_fmaf(p, t, -1.453152027f);
  p = __builtin_fmaf(p, t, 1.421413741f);
  p = __builtin_fmaf(p, t, -0.284496736f);
  p = __builtin_fmaf(p, t, 0.254829592f);
  p = p * t;
  float e = __expf(-u * u);
  float erf_a = 1.0f - p * e;
  float erf_u = copysignf(erf_a, u);
  return 0.5f * v * (1.0f + erf_u);
}

__device__ inline float gelu_exact(float v) {
  return 0.5f * v * (1.0f + erff(v * 0.70710678118f));
}

// ---------------- pre-transpose + bf16 cast: src [E][R][Cc] f32 -> dst [E][Cc][R] bf16 ----------------
__global__ void transpose_cvt(const float* __restrict__ src, unsigned short* __restrict__ dst,
                              int R, int Cc) {
  __shared__ alignas(16) float tile[32][33];
  int tilesC = Cc >> 5;
  int per_e  = (R >> 5) * tilesC;
  int e  = blockIdx.x / per_e;
  int t  = blockIdx.x % per_e;
  int tr = t / tilesC, tc = t % tilesC;
  const float* s = src + (size_t)e * R * Cc;
  unsigned short* d = dst + (size_t)e * R * Cc;
  int tx = threadIdx.x & 31, ty = threadIdx.x >> 5;
  for (int i = ty; i < 32; i += 8)
    tile[i][tx] = s[(size_t)(tr * 32 + i) * Cc + tc * 32 + tx];
  __syncthreads();
  for (int i = ty; i < 32; i += 8)
    d[(size_t)(tc * 32 + i) * R + tr * 32 + tx] = f2bf(tile[tx][i]);
}

__global__ void zero_scalar(float* p) {
  if (threadIdx.x == 0 && blockIdx.x == 0) *p = 0.0f;
}

// ---------------- fused per-expert MLP ----------------
// GEMM1: hT[c][r] = sum_k w1T[c][k] * x[r][k]   (A = w1T-frags from global, B = x from LDS)
// GEMM2: yT[d][r] = sum_c w2T[d][c] * h[r][c]   (A = w2T-frags from global, B = h from LDS)
__global__ __launch_bounds__(THREADS, 4) void experts_mlp(
    const float* __restrict__ x, const float* __restrict__ b1,
    const float* __restrict__ b2, const float* __restrict__ bungee,
    const unsigned short* __restrict__ w1t, const unsigned short* __restrict__ w2t,
    float* __restrict__ y, float* __restrict__ sumsq) {
  // x tile, bf16, XOR-swizzled: addr = row*512 + (cb ^ ((row&7)<<6)); 32 KiB
  __shared__ alignas(16) unsigned char x_sw[BM * 512];
  __shared__ alignas(16) short h_lds[BM][BH + 8];   // 17.4 KiB, +8 pad
  __shared__ float red[NWAVE];

  // XCD-chunked swizzle: 2048 wgs, 8 XCDs -> 4 consecutive experts per XCD
  int bid = blockIdx.x;
  int wg  = (bid & 7) * (NWG / 8) + (bid >> 3);
  int e   = wg >> 6;
  int r0  = (wg & 63) * BM;

  int tid  = threadIdx.x;
  int wid  = tid >> 6;
  int lane = tid & 63;
  int lr   = lane & 15;
  int lg   = lane >> 4;
  int lr7  = lr & 7;

  // ---- stage x tile -> LDS (f32 -> bf16, swizzled). 4096 float4, 512 thr x 8.
  {
    const float* xb = x + ((size_t)e * NC + r0) * ND;
    #pragma unroll
    for (int j = 0; j < 8; ++j) {
      int f   = j * 512 + tid;        // float4 index in tile
      int row = f >> 6;               // 64 float4 per row
      int c16 = f & 63;
      float4v u = *(const float4v*)(xb + (size_t)f * 4);
      bf16x4 s;
      s[0] = (__bf16)u[0]; s[1] = (__bf16)u[1]; s[2] = (__bf16)u[2]; s[3] = (__bf16)u[3];
      int cb = c16 * 8;               // byte col in bf16 row
      *(bf16x4*)(x_sw + row * 512 + (cb ^ ((row & 7) << 6))) = s;
    }
  }
  __syncthreads();

  f32x4 zero4 = {0.f, 0.f, 0.f, 0.f};
  f32x4 acc2[2][4];
  #pragma unroll
  for (int mf = 0; mf < 2; ++mf)
    #pragma unroll
    for (int nf = 0; nf < 4; ++nf) acc2[mf][nf] = zero4;

  const unsigned short* w1row = w1t + ((size_t)e * NH + wid * 16 + lr) * ND;
  const unsigned short* w2row = w2t + ((size_t)e * ND + wid * 32 + lr) * NH;

  for (int hs = 0; hs < NSTEP; ++hs) {
    // ---- GEMM1: wave computes hT cols [hs*BH + wid*16, +16) x rows [0,64)
    bf16x8 a1[8];
    const unsigned short* wr = w1row + (size_t)hs * BH * ND;
    #pragma unroll
    for (int ks = 0; ks < 8; ++ks)
      a1[ks] = __builtin_bit_cast(bf16x8, *(const short8v*)(wr + ks * 32 + lg * 8));

    f32x4 acc1[4];
    #pragma unroll
    for (int nf = 0; nf < 4; ++nf) acc1[nf] = zero4;
    #pragma unroll
    for (int ks = 0; ks < 8; ++ks) {
      int kx = (ks ^ lr7) * 64 + lg * 16;   // swizzled byte col (bits disjoint)
      #pragma unroll
      for (int nf = 0; nf < 4; ++nf) {
        int row = nf * 16 + lr;
        bf16x8 xv = *(const bf16x8*)(x_sw + row * 512 + kx);
        acc1[nf] = mfma16(a1[ks], xv, acc1[nf]);
      }
    }

    // ---- bias + GELU -> h_lds. C/D layout: col(=r)=lane&15, row(=c)=(lane>>4)*4+reg
    int clocal = wid * 16 + lg * 4;
    const float* b1p = b1 + (size_t)e * NH + hs * BH + clocal;
    float4v bv = *(const float4v*)b1p;
    #pragma unroll
    for (int nf = 0; nf < 4; ++nf) {
      bf16x4 p;
      #pragma unroll
      for (int reg = 0; reg < 4; ++reg)
        p[reg] = (__bf16)gelu_fast(acc1[nf][reg] + bv[reg]);
      *(bf16x4*)&h_lds[nf * 16 + lr][clocal] = p;
    }
    __syncthreads();

    // ---- GEMM2: wave computes yT rows d in [wid*32, +32), k over this h block
    const unsigned short* w2p = w2row + (size_t)hs * BH;
    #pragma unroll
    for (int ks = 0; ks < 4; ++ks) {
      bf16x8 a20 = __builtin_bit_cast(bf16x8, *(const short8v*)(w2p + ks * 32 + lg * 8));
      bf16x8 a21 = __builtin_bit_cast(bf16x8, *(const short8v*)(w2p + (size_t)16 * NH + ks * 32 + lg * 8));
      #pragma unroll
      for (int nf = 0; nf < 4; ++nf) {
        bf16x8 hb = __builtin_bit_cast(bf16x8, *(const short8v*)&h_lds[nf * 16 + lr][ks * 32 + lg * 8]);
        acc2[0][nf] = mfma16(a20, hb, acc2[0][nf]);
        acc2[1][nf] = mfma16(a21, hb, acc2[1][nf]);
      }
    }
    __syncthreads();
  }

  // ---- epilogue: bias2 + bungee + store + sumsq
  float bg = bungee[e];
  float ss = 0.0f;
  int dbase = wid * 32 + lg * 4;
  #pragma unroll
  for (int mf = 0; mf < 2; ++mf) {
    int dd = dbase + mf * 16;
    float4v b2v = *(const float4v*)(b2 + (size_t)e * ND + dd);
    #pragma unroll
    for (int nf = 0; nf < 4; ++nf) {
      int r = r0 + nf * 16 + lr;
      float4v o;
      #pragma unroll
      for (int reg = 0; reg < 4; ++reg) {
        float v = (acc2[mf][nf][reg] + b2v[reg]) * bg;
        o[reg] = v;
        ss += v * v;
      }
      *(float4v*)(y + ((size_t)e * NC + r) * ND + dd) = o;
    }
  }
  #pragma unroll
  for (int off = 32; off > 0; off >>= 1) ss += __shfl_down(ss, off);
  if (lane == 0) red[wid] = ss;
  __syncthreads();
  if (tid == 0) {
    float t = 0.f;
    #pragma unroll
    for (int i = 0; i < NWAVE; ++i) t += red[i];
    atomicAdd(sumsq, t);
  }
}

// ---------------- fallback path: zero workspace, fp32 VALU ----------------
#define FBROWS 8
__global__ __launch_bounds__(256) void fb_mlp(
    const float* __restrict__ x, const float* __restrict__ w1, const float* __restrict__ b1,
    const float* __restrict__ w2, const float* __restrict__ b2, const float* __restrict__ bungee,
    float* __restrict__ y, float* __restrict__ sumsq) {
  __shared__ alignas(16) float xs[FBROWS][ND];
  __shared__ alignas(16) float hsh[FBROWS][NH];
  __shared__ float red[4];
  int tid = threadIdx.x;
  int e  = blockIdx.x / (NC / FBROWS);
  int r0 = (blockIdx.x % (NC / FBROWS)) * FBROWS;

  for (int i = tid; i < FBROWS * ND; i += 256)
    ((float*)xs)[i] = x[((size_t)e * NC + r0) * ND + i];
  __syncthreads();

  for (int c = tid; c < NH; c += 256) {
    float acc[FBROWS];
    float bb = b1[(size_t)e * NH + c];
    #pragma unroll
    for (int rr = 0; rr < FBROWS; ++rr) acc[rr] = bb;
    for (int k = 0; k < ND; ++k) {
      float w = w1[((size_t)e * ND + k) * NH + c];
      #pragma unroll
      for (int rr = 0; rr < FBROWS; ++rr) acc[rr] += xs[rr][k] * w;
    }
    #pragma unroll
    for (int rr = 0; rr < FBROWS; ++rr) hsh[rr][c] = gelu_exact(acc[rr]);
  }
  __syncthreads();

  int d = tid;
  float acc[FBROWS];
  float bb = b2[(size_t)e * ND + d];
  #pragma unroll
  for (int rr = 0; rr < FBROWS; ++rr) acc[rr] = bb;
  for (int c = 0; c < NH; ++c) {
    float w = w2[((size_t)e * NH + c) * ND + d];
    #pragma unroll
    for (int rr = 0; rr < FBROWS; ++rr) acc[rr] += hsh[rr][c] * w;
  }
  float bg = bungee[e];
  float ss = 0.f;
  #pragma unroll
  for (int rr = 0; rr < FBROWS; ++rr) {
    float v = acc[rr] * bg;
    y[((size_t)e * NC + r0 + rr) * ND + d] = v;
    ss += v * v;
  }
  #pragma unroll
  for (int off = 32; off > 0; off >>= 1) ss += __shfl_down(ss, off);
  if ((tid & 63) == 0) red[tid >> 6] = ss;
  __syncthreads();
  if (tid == 0) atomicAdd(sumsq, red[0] + red[1] + red[2] + red[3]);
}

// ---------------- scalars (sumsq accumulates in out_scalars[0]) ----------------
__global__ void finalize(const float* __restrict__ bungee, float* __restrict__ out_scalars) {
  if (threadIdx.x == 0 && blockIdx.x == 0) {
    float ss = out_scalars[0];
    out_scalars[0] = sqrtf(ss / (float)TOTY);
    float m = 0.f, mn = bungee[0], mx = bungee[0];
    for (int i = 0; i < NE; ++i) {
      float b = bungee[i];
      m += b; mn = fminf(mn, b); mx = fmaxf(mx, b);
    }
    out_scalars[1] = m / (float)NE;
    out_scalars[2] = mn;
    out_scalars[3] = mx;
  }
}

extern "C" void kernel_launch(void* const* d_in, const int* in_sizes, int n_in,
                              void* d_out, int out_size, void* d_ws, size_t ws_size,
                              hipStream_t stream) {
  (void)in_sizes; (void)n_in; (void)out_size;
  const float* x  = (const float*)d_in[0];
  const float* w1 = (const float*)d_in[1];
  const float* b1 = (const float*)d_in[2];
  const float* w2 = (const float*)d_in[3];
  const float* b2 = (const float*)d_in[4];
  const float* bg = (const float*)d_in[5];
  float* out = (float*)d_out;
  float* rms_slot = out + TOTY;

  const size_t WS_NEEDED = (size_t)NE * ND * NH * 2 * 2;  // 32 MiB

  zero_scalar<<<1, 1, 0, stream>>>(rms_slot);
  if (ws_size >= WS_NEEDED) {
    unsigned short* w1t = (unsigned short*)d_ws;
    unsigned short* w2t = w1t + (size_t)NE * ND * NH;
    transpose_cvt<<<NE * (ND / 32) * (NH / 32), 256, 0, stream>>>(w1, w1t, ND, NH);
    transpose_cvt<<<NE * (NH / 32) * (ND / 32), 256, 0, stream>>>(w2, w2t, NH, ND);
    experts_mlp<<<NWG, THREADS, 0, stream>>>(x, b1, b2, bg, w1t, w2t, out, rms_slot);
  } else {
    fb_mlp<<<NE * NC / FBROWS, 256, 0, stream>>>(x, w1, b1, w2, b2, bg, out, rms_slot);
  }
  finalize<<<1, 64, 0, stream>>>(bg, rms_slot);
}

// Round 10
// 520.842 us; speedup vs baseline: 1.4736x; 1.0506x over previous
//
#include <hip/hip_runtime.h>
#include <cmath>

#define NE 32
#define NC 4096
#define ND 256
#define NH 1024
#define BM 64            // x/y rows per workgroup
#define BH 128           // h columns per step
#define NSTEP (NH / BH)  // 8
#define NWAVE 8
#define THREADS (NWAVE * 64)
#define NWG (NE * NC / BM)  // 2048
#define TOTY ((size_t)NE * NC * ND)

typedef float  float4v __attribute__((ext_vector_type(4)));
typedef float  f32x4   __attribute__((ext_vector_type(4)));
typedef short  short8v __attribute__((ext_vector_type(8)));
typedef short  short4v __attribute__((ext_vector_type(4)));
typedef __bf16 bf16x8  __attribute__((ext_vector_type(8)));
typedef __bf16 bf16x4  __attribute__((ext_vector_type(4)));

__device__ inline unsigned short f2bf(float f) {
  unsigned int u = __float_as_uint(f);
  u += 0x7fffu + ((u >> 16) & 1u);
  return (unsigned short)(u >> 16);
}

__device__ inline f32x4 mfma16(bf16x8 a, bf16x8 b, f32x4 c) {
  return __builtin_amdgcn_mfma_f32_16x16x32_bf16(a, b, c, 0, 0, 0);
}

// Fast exact-GELU: Abramowitz-Stegun 7.1.26 erf (|err|<=1.5e-7), ~13 VALU ops.
__device__ inline float gelu_fast(float v) {
  float u = v * 0.70710678118f;
  float a = fabsf(u);
  float t = __builtin_amdgcn_rcpf(__builtin_fmaf(0.3275911f, a, 1.0f));
  float p = 1.061405429f;
  p = __builtin_fmaf(p, t, -1.453152027f);
  p = __builtin_fmaf(p, t, 1.421413741f);
  p = __builtin_fmaf(p, t, -0.284496736f);
  p = __builtin_fmaf(p, t, 0.254829592f);
  p = p * t;
  float e = __expf(-u * u);
  float erf_a = 1.0f - p * e;
  float erf_u = copysignf(erf_a, u);
  return 0.5f * v * (1.0f + erf_u);
}

__device__ inline float gelu_exact(float v) {
  return 0.5f * v * (1.0f + erff(v * 0.70710678118f));
}

// ---------------- prep: zero rms slot + transpose+cvt both weights in one launch ----------------
// blocks [0, 8192): w1 [E][D][H] -> w1t [E][H][D];  [8192, 16384): w2 [E][H][D'] -> w2t [E][D'][H]
__global__ void prep(const float* __restrict__ w1, const float* __restrict__ w2,
                     unsigned short* __restrict__ w1t, unsigned short* __restrict__ w2t,
                     float* __restrict__ rms_slot) {
  if (blockIdx.x == 0 && threadIdx.x == 0) *rms_slot = 0.0f;
  __shared__ alignas(16) float tile[32][33];
  int b = blockIdx.x;
  const float* src; unsigned short* dst; int R, Cc;
  if (b < 8192) { src = w1; dst = w1t; R = ND; Cc = NH; }
  else          { b -= 8192; src = w2; dst = w2t; R = NH; Cc = ND; }
  int tilesC = Cc >> 5;
  int per_e  = (R >> 5) * tilesC;
  int e  = b / per_e;
  int t  = b % per_e;
  int tr = t / tilesC, tc = t % tilesC;
  const float* s = src + (size_t)e * R * Cc;
  unsigned short* d = dst + (size_t)e * R * Cc;
  int tx = threadIdx.x & 31, ty = threadIdx.x >> 5;
  for (int i = ty; i < 32; i += 8)
    tile[i][tx] = s[(size_t)(tr * 32 + i) * Cc + tc * 32 + tx];
  __syncthreads();
  for (int i = ty; i < 32; i += 8)
    d[(size_t)(tc * 32 + i) * R + tr * 32 + tx] = f2bf(tile[tx][i]);
}

__global__ void zero_scalar(float* p) {
  if (threadIdx.x == 0 && blockIdx.x == 0) *p = 0.0f;
}

// ---------------- fused per-expert MLP ----------------
// GEMM1: hT[c][r] = sum_k w1T[c][k] * x[r][k]   (A = w1T-frags prefetched, B = x from LDS)
// GEMM2: yT[d][r] = sum_c w2T[d][c] * h[r][c]   (A = w2T-frags prefetched, B = h from LDS)
__global__ __launch_bounds__(THREADS, 4) void experts_mlp(
    const float* __restrict__ x, const float* __restrict__ b1,
    const float* __restrict__ b2, const float* __restrict__ bungee,
    const unsigned short* __restrict__ w1t, const unsigned short* __restrict__ w2t,
    float* __restrict__ y, float* __restrict__ sumsq) {
  // x tile, bf16, XOR-swizzled: addr = row*512 + (cb ^ ((row&7)<<6)); 32 KiB
  __shared__ alignas(16) unsigned char x_sw[BM * 512];
  __shared__ alignas(16) short h_lds[BM][BH + 8];   // +8 pad
  __shared__ float red[NWAVE];

  // XCD-chunked swizzle: 2048 wgs, 8 XCDs -> 4 consecutive experts per XCD
  int bid = blockIdx.x;
  int wg  = (bid & 7) * (NWG / 8) + (bid >> 3);
  int e   = wg >> 6;
  int r0  = (wg & 63) * BM;

  int tid  = threadIdx.x;
  int wid  = tid >> 6;
  int lane = tid & 63;
  int lr   = lane & 15;
  int lg   = lane >> 4;
  int lr7  = lr & 7;

  // ---- stage x tile -> LDS (f32 -> bf16, swizzled). 4096 float4, 512 thr x 8.
  {
    const float* xb = x + ((size_t)e * NC + r0) * ND;
    #pragma unroll
    for (int j = 0; j < 8; ++j) {
      int f   = j * 512 + tid;        // float4 index in tile
      int row = f >> 6;               // 64 float4 per row
      int c16 = f & 63;
      float4v u = *(const float4v*)(xb + (size_t)f * 4);
      bf16x4 s;
      s[0] = (__bf16)u[0]; s[1] = (__bf16)u[1]; s[2] = (__bf16)u[2]; s[3] = (__bf16)u[3];
      int cb = c16 * 8;               // byte col in bf16 row
      *(bf16x4*)(x_sw + row * 512 + (cb ^ ((row & 7) << 6))) = s;
    }
  }

  f32x4 zero4 = {0.f, 0.f, 0.f, 0.f};
  f32x4 acc2[2][4];
  #pragma unroll
  for (int mf = 0; mf < 2; ++mf)
    #pragma unroll
    for (int nf = 0; nf < 4; ++nf) acc2[mf][nf] = zero4;

  const unsigned short* w1row = w1t + ((size_t)e * NH + wid * 16 + lr) * ND;
  const unsigned short* w2row = w2t + ((size_t)e * ND + wid * 32 + lr) * NH;

  // ---- prologue: a1 fragments for hs=0 (land while x staging + first barrier drain)
  bf16x8 a1[8];
  #pragma unroll
  for (int ks = 0; ks < 8; ++ks)
    a1[ks] = __builtin_bit_cast(bf16x8, *(const short8v*)(w1row + ks * 32 + lg * 8));

  __syncthreads();   // x_sw ready

  for (int hs = 0; hs < NSTEP; ++hs) {
    // ---- prefetch w2 fragments for THIS step (consumed after the barrier,
    //      latency hidden under GEMM1 + GELU). 8 x b128.
    const unsigned short* w2p = w2row + (size_t)hs * BH;
    bf16x8 w2f0[4], w2f1[4];
    #pragma unroll
    for (int ks = 0; ks < 4; ++ks) {
      w2f0[ks] = __builtin_bit_cast(bf16x8, *(const short8v*)(w2p + ks * 32 + lg * 8));
      w2f1[ks] = __builtin_bit_cast(bf16x8, *(const short8v*)(w2p + (size_t)16 * NH + ks * 32 + lg * 8));
    }

    // ---- GEMM1: wave computes hT cols [hs*BH + wid*16, +16) x rows [0,64)
    f32x4 acc1[4];
    #pragma unroll
    for (int nf = 0; nf < 4; ++nf) acc1[nf] = zero4;
    #pragma unroll
    for (int ks = 0; ks < 8; ++ks) {
      int kx = (ks ^ lr7) * 64 + lg * 16;   // swizzled byte col (bits disjoint)
      #pragma unroll
      for (int nf = 0; nf < 4; ++nf) {
        int row = nf * 16 + lr;
        bf16x8 xv = *(const bf16x8*)(x_sw + row * 512 + kx);
        acc1[nf] = mfma16(a1[ks], xv, acc1[nf]);
      }
    }

    // ---- refill a1 for NEXT step (same registers; hidden under GELU+barrier+GEMM2)
    if (hs + 1 < NSTEP) {
      const unsigned short* wr = w1row + (size_t)(hs + 1) * BH * ND;
      #pragma unroll
      for (int ks = 0; ks < 8; ++ks)
        a1[ks] = __builtin_bit_cast(bf16x8, *(const short8v*)(wr + ks * 32 + lg * 8));
    }

    // ---- bias + GELU -> h_lds. C/D layout: col(=r)=lane&15, row(=c)=(lane>>4)*4+reg
    int clocal = wid * 16 + lg * 4;
    const float* b1p = b1 + (size_t)e * NH + hs * BH + clocal;
    float4v bv = *(const float4v*)b1p;
    #pragma unroll
    for (int nf = 0; nf < 4; ++nf) {
      bf16x4 p;
      #pragma unroll
      for (int reg = 0; reg < 4; ++reg)
        p[reg] = (__bf16)gelu_fast(acc1[nf][reg] + bv[reg]);
      *(bf16x4*)&h_lds[nf * 16 + lr][clocal] = p;
    }
    __syncthreads();

    // ---- GEMM2: wave computes yT rows d in [wid*32, +32), k over this h block
    #pragma unroll
    for (int ks = 0; ks < 4; ++ks) {
      #pragma unroll
      for (int nf = 0; nf < 4; ++nf) {
        bf16x8 hb = __builtin_bit_cast(bf16x8, *(const short8v*)&h_lds[nf * 16 + lr][ks * 32 + lg * 8]);
        acc2[0][nf] = mfma16(w2f0[ks], hb, acc2[0][nf]);
        acc2[1][nf] = mfma16(w2f1[ks], hb, acc2[1][nf]);
      }
    }
    __syncthreads();
  }

  // ---- epilogue: bias2 + bungee + store + sumsq
  float bg = bungee[e];
  float ss = 0.0f;
  int dbase = wid * 32 + lg * 4;
  #pragma unroll
  for (int mf = 0; mf < 2; ++mf) {
    int dd = dbase + mf * 16;
    float4v b2v = *(const float4v*)(b2 + (size_t)e * ND + dd);
    #pragma unroll
    for (int nf = 0; nf < 4; ++nf) {
      int r = r0 + nf * 16 + lr;
      float4v o;
      #pragma unroll
      for (int reg = 0; reg < 4; ++reg) {
        float v = (acc2[mf][nf][reg] + b2v[reg]) * bg;
        o[reg] = v;
        ss += v * v;
      }
      *(float4v*)(y + ((size_t)e * NC + r) * ND + dd) = o;
    }
  }
  #pragma unroll
  for (int off = 32; off > 0; off >>= 1) ss += __shfl_down(ss, off);
  if (lane == 0) red[wid] = ss;
  __syncthreads();
  if (tid == 0) {
    float t = 0.f;
    #pragma unroll
    for (int i = 0; i < NWAVE; ++i) t += red[i];
    atomicAdd(sumsq, t);
  }
}

// ---------------- fallback path: zero workspace, fp32 VALU ----------------
#define FBROWS 8
__global__ __launch_bounds__(256) void fb_mlp(
    const float* __restrict__ x, const float* __restrict__ w1, const float* __restrict__ b1,
    const float* __restrict__ w2, const float* __restrict__ b2, const float* __restrict__ bungee,
    float* __restrict__ y, float* __restrict__ sumsq) {
  __shared__ alignas(16) float xs[FBROWS][ND];
  __shared__ alignas(16) float hsh[FBROWS][NH];
  __shared__ float red[4];
  int tid = threadIdx.x;
  int e  = blockIdx.x / (NC / FBROWS);
  int r0 = (blockIdx.x % (NC / FBROWS)) * FBROWS;

  for (int i = tid; i < FBROWS * ND; i += 256)
    ((float*)xs)[i] = x[((size_t)e * NC + r0) * ND + i];
  __syncthreads();

  for (int c = tid; c < NH; c += 256) {
    float acc[FBROWS];
    float bb = b1[(size_t)e * NH + c];
    #pragma unroll
    for (int rr = 0; rr < FBROWS; ++rr) acc[rr] = bb;
    for (int k = 0; k < ND; ++k) {
      float w = w1[((size_t)e * ND + k) * NH + c];
      #pragma unroll
      for (int rr = 0; rr < FBROWS; ++rr) acc[rr] += xs[rr][k] * w;
    }
    #pragma unroll
    for (int rr = 0; rr < FBROWS; ++rr) hsh[rr][c] = gelu_exact(acc[rr]);
  }
  __syncthreads();

  int d = tid;
  float acc[FBROWS];
  float bb = b2[(size_t)e * ND + d];
  #pragma unroll
  for (int rr = 0; rr < FBROWS; ++rr) acc[rr] = bb;
  for (int c = 0; c < NH; ++c) {
    float w = w2[((size_t)e * NH + c) * ND + d];
    #pragma unroll
    for (int rr = 0; rr < FBROWS; ++rr) acc[rr] += hsh[rr][c] * w;
  }
  float bg = bungee[e];
  float ss = 0.f;
  #pragma unroll
  for (int rr = 0; rr < FBROWS; ++rr) {
    float v = acc[rr] * bg;
    y[((size_t)e * NC + r0 + rr) * ND + d] = v;
    ss += v * v;
  }
  #pragma unroll
  for (int off = 32; off > 0; off >>= 1) ss += __shfl_down(ss, off);
  if ((tid & 63) == 0) red[tid >> 6] = ss;
  __syncthreads();
  if (tid == 0) atomicAdd(sumsq, red[0] + red[1] + red[2] + red[3]);
}

// ---------------- scalars (sumsq accumulates in out_scalars[0]) ----------------
__global__ void finalize(const float* __restrict__ bungee, float* __restrict__ out_scalars) {
  if (threadIdx.x == 0 && blockIdx.x == 0) {
    float ss = out_scalars[0];
    out_scalars[0] = sqrtf(ss / (float)TOTY);
    float m = 0.f, mn = bungee[0], mx = bungee[0];
    for (int i = 0; i < NE; ++i) {
      float b = bungee[i];
      m += b; mn = fminf(mn, b); mx = fmaxf(mx, b);
    }
    out_scalars[1] = m / (float)NE;
    out_scalars[2] = mn;
    out_scalars[3] = mx;
  }
}

extern "C" void kernel_launch(void* const* d_in, const int* in_sizes, int n_in,
                              void* d_out, int out_size, void* d_ws, size_t ws_size,
                              hipStream_t stream) {
  (void)in_sizes; (void)n_in; (void)out_size;
  const float* x  = (const float*)d_in[0];
  const float* w1 = (const float*)d_in[1];
  const float* b1 = (const float*)d_in[2];
  const float* w2 = (const float*)d_in[3];
  const float* b2 = (const float*)d_in[4];
  const float* bg = (const float*)d_in[5];
  float* out = (float*)d_out;
  float* rms_slot = out + TOTY;

  const size_t WS_NEEDED = (size_t)NE * ND * NH * 2 * 2;  // 32 MiB

  if (ws_size >= WS_NEEDED) {
    unsigned short* w1t = (unsigned short*)d_ws;
    unsigned short* w2t = w1t + (size_t)NE * ND * NH;
    prep<<<16384, 256, 0, stream>>>(w1, w2, w1t, w2t, rms_slot);
    experts_mlp<<<NWG, THREADS, 0, stream>>>(x, b1, b2, bg, w1t, w2t, out, rms_slot);
  } else {
    zero_scalar<<<1, 1, 0, stream>>>(rms_slot);
    fb_mlp<<<NE * NC / FBROWS, 256, 0, stream>>>(x, w1, b1, w2, b2, bg, out, rms_slot);
  }
  finalize<<<1, 64, 0, stream>>>(bg, rms_slot);
}